// Round 2
// baseline (849.973 us; speedup 1.0000x reference)
//
#include <hip/hip_runtime.h>

// VQ-VAE EMA quantizer. B=32, D=64, T=2048, K=1024, N=B*T=65536.
// Outputs (f32, concat): quantized[32*64*2048], loss[1], codes[32*2048],
//   new_embedding[1024*64], new_cs[1024], new_w[1024*64]  -> 4391937 total.

constexpr int Bn = 32, Dn = 64, Tn = 2048, Kn = 1024;
constexpr float DECAY = 0.99f, ONE_MINUS_DECAY = 0.01f, EPSV = 1e-5f, COMMIT = 0.25f;

// ---------------- esq: per-code squared norm ----------------
__global__ __launch_bounds__(256) void vq_esq_kernel(const float* __restrict__ emb,
                                                     float* __restrict__ esq) {
  int k = blockIdx.x * 256 + threadIdx.x;
  if (k >= Kn) return;
  const float4* e4 = reinterpret_cast<const float4*>(emb + (size_t)k * Dn);
  float a0 = 0.f, a1 = 0.f, a2 = 0.f, a3 = 0.f;
#pragma unroll
  for (int q = 0; q < 16; ++q) {
    float4 v = e4[q];
    a0 = fmaf(v.x, v.x, a0);
    a1 = fmaf(v.y, v.y, a1);
    a2 = fmaf(v.z, v.z, a2);
    a3 = fmaf(v.w, v.w, a3);
  }
  esq[k] = (a0 + a1) + (a2 + a3);
}

// ---------------- main: distances, argmin, quant, loss, segment sums ----------------
// Block: 256 threads = 32 tokens (same b, consecutive t). Thread (tc = tid&31,
// dg = tid>>5) computes token tc's distances over codes [dg*128, dg*128+128).
__global__ __launch_bounds__(256) void vq_main_kernel(
    const float* __restrict__ z, const float* __restrict__ emb,
    const float* __restrict__ esq, float* __restrict__ out_quant,
    float* __restrict__ out_codes, float* __restrict__ counts,
    float* __restrict__ dw, float* __restrict__ loss_acc) {
  __shared__ float zs[32][68];   // stride 68 floats = 272 B (16B aligned)
  __shared__ float red_d[8][32];
  __shared__ int   red_i[8][32];
  __shared__ int   idxs[32];
  __shared__ float lred[4];

  const int tid = threadIdx.x;
  const int blk = blockIdx.x;
  const int b = blk >> 6;            // 64 blocks per batch element
  const int t0 = (blk & 63) * 32;

  const int tc = tid & 31;           // token within tile
  const int dg = tid >> 5;           // code-slab / d-group 0..7

  // ---- stage z tile: zs[token][d], coalesced along t ----
  const float* zb = z + (size_t)b * Dn * Tn;
#pragma unroll
  for (int j = 0; j < 8; ++j) {
    int d = dg * 8 + j;
    zs[tc][d] = zb[(size_t)d * Tn + t0 + tc];
  }
  __syncthreads();

  // ---- distances + per-thread argmin ----
  float zr[64];
#pragma unroll
  for (int d = 0; d < 64; ++d) zr[d] = zs[tc][d];
  float zsq = 0.f;
#pragma unroll
  for (int d = 0; d < 64; ++d) zsq = fmaf(zr[d], zr[d], zsq);

  float mind = INFINITY;
  int midx = 0;
  const float4* e4 = reinterpret_cast<const float4*>(emb);
  const int c0 = dg * 128;
  for (int c = c0; c < c0 + 128; ++c) {
    float a0 = 0.f, a1 = 0.f, a2 = 0.f, a3 = 0.f;
#pragma unroll
    for (int q = 0; q < 16; ++q) {
      float4 ev = e4[(size_t)c * 16 + q];
      a0 = fmaf(zr[q * 4 + 0], ev.x, a0);
      a1 = fmaf(zr[q * 4 + 1], ev.y, a1);
      a2 = fmaf(zr[q * 4 + 2], ev.z, a2);
      a3 = fmaf(zr[q * 4 + 3], ev.w, a3);
    }
    float dot = (a0 + a1) + (a2 + a3);
    float dist = fmaf(-2.f, dot, zsq + esq[c]);
    if (dist < mind) { mind = dist; midx = c; }   // ascending c => first min kept
  }
  red_d[dg][tc] = mind;
  red_i[dg][tc] = midx;
  __syncthreads();

  // ---- cross-slab argmin reduce, codes, counts ----
  if (tid < 32) {
    float md = red_d[0][tid];
    int mi = red_i[0][tid];
#pragma unroll
    for (int s = 1; s < 8; ++s) {
      float dv = red_d[s][tid];
      int iv = red_i[s][tid];
      if (dv < md || (dv == md && iv < mi)) { md = dv; mi = iv; }
    }
    idxs[tid] = mi;
    out_codes[(size_t)b * Tn + t0 + tid] = (float)mi;
    atomicAdd(&counts[mi], 1.0f);
  }
  __syncthreads();

  // ---- quantized output (coalesced along t), dw segment sum, direct loss ----
  const int myidx = idxs[tc];
  const float* erow = emb + (size_t)myidx * Dn;
  float* qout = out_quant + (size_t)b * Dn * Tn;
  float lpart = 0.f;
#pragma unroll
  for (int j = 0; j < 8; ++j) {
    int d = dg * 8 + j;
    float e = erow[d];
    float zv = zs[tc][d];
    qout[(size_t)d * Tn + t0 + tc] = e;
    atomicAdd(&dw[(size_t)myidx * Dn + d], zv);
    float diff = e - zv;
    lpart = fmaf(diff, diff, lpart);   // reference's direct (quant - z)^2
  }
  // block-reduce loss partial: wave shuffle then LDS across the 4 waves
#pragma unroll
  for (int off = 32; off > 0; off >>= 1) lpart += __shfl_down(lpart, off, 64);
  if ((tid & 63) == 0) lred[tid >> 6] = lpart;
  __syncthreads();
  if (tid == 0) atomicAdd(loss_acc, (lred[0] + lred[1]) + (lred[2] + lred[3]));
}

// ---------------- finalize part 1: new_cs, n, loss ----------------
__global__ __launch_bounds__(1024) void vq_final1_kernel(
    const float* __restrict__ ema_cs, const float* __restrict__ counts,
    const float* __restrict__ loss_acc, float* __restrict__ out_newcs,
    float* __restrict__ out_loss, float* __restrict__ n_out) {
  __shared__ float sred[1024];
  const int tid = threadIdx.x;
  float cs = fmaf(ONE_MINUS_DECAY, counts[tid], DECAY * ema_cs[tid]);
  out_newcs[tid] = cs;
  sred[tid] = cs;
  __syncthreads();
  for (int s = 512; s > 0; s >>= 1) {
    if (tid < s) sred[tid] += sred[tid + s];
    __syncthreads();
  }
  if (tid == 0) {
    n_out[0] = sred[0];
    out_loss[0] = COMMIT * loss_acc[0] / (float)(Bn * Tn * Dn);
  }
}

// ---------------- finalize part 2: new_w, new_embedding ----------------
__global__ __launch_bounds__(256) void vq_final2_kernel(
    const float* __restrict__ ema_w, const float* __restrict__ dw,
    const float* __restrict__ newcs, const float* __restrict__ n_in,
    float* __restrict__ out_neww, float* __restrict__ out_newemb) {
  const int i = blockIdx.x * 256 + threadIdx.x;   // 0..65535
  const int k = i >> 6;
  const float n = n_in[0];
  const float cl = (newcs[k] + EPSV) / (n + (float)Kn * EPSV) * n;
  const float w = fmaf(ONE_MINUS_DECAY, dw[i], DECAY * ema_w[i]);
  out_neww[i] = w;
  out_newemb[i] = w / cl;
}

extern "C" void kernel_launch(void* const* d_in, const int* in_sizes, int n_in,
                              void* d_out, int out_size, void* d_ws, size_t ws_size,
                              hipStream_t stream) {
  const float* z      = (const float*)d_in[0];
  const float* emb    = (const float*)d_in[1];
  const float* ema_cs = (const float*)d_in[2];
  const float* ema_w  = (const float*)d_in[3];

  float* out = (float*)d_out;
  float* o_quant  = out;                       // 4194304
  float* o_loss   = out + 4194304;             // 1
  float* o_codes  = out + 4194305;             // 65536
  float* o_newemb = out + 4259841;             // 65536
  float* o_newcs  = out + 4325377;             // 1024
  float* o_neww   = out + 4326401;             // 65536

  float* ws       = (float*)d_ws;
  float* counts   = ws;                        // 1024
  float* dw       = ws + 1024;                 // 65536
  float* loss_acc = ws + 66560;                // 1
  float* nval     = ws + 66561;                // 1
  float* esq      = ws + 66562;                // 1024

  // zero counts + dw + loss accumulator (ws is poisoned 0xAA before each call)
  hipMemsetAsync(ws, 0, (size_t)66561 * sizeof(float), stream);

  vq_esq_kernel<<<4, 256, 0, stream>>>(emb, esq);
  vq_main_kernel<<<2048, 256, 0, stream>>>(z, emb, esq, o_quant, o_codes,
                                           counts, dw, loss_acc);
  vq_final1_kernel<<<1, 1024, 0, stream>>>(ema_cs, counts, loss_acc,
                                           o_newcs, o_loss, nval);
  vq_final2_kernel<<<256, 256, 0, stream>>>(ema_w, dw, o_newcs, nval,
                                            o_neww, o_newemb);
}